// Round 1
// baseline (188.784 us; speedup 1.0000x reference)
//
#include <hip/hip_runtime.h>
#include <hip/hip_bf16.h>

#define NP 4096      // N
#define DD 128       // D
#define N2 8192      // 2N
#define GAMMA1 0.02f // 1/(2*5^2), cont label
#define TINV 10.0f   // 1/temperature
#define SHIFT 10.0f  // fixed log-sum-exp shift (sim <= 10)

typedef __attribute__((ext_vector_type(8))) short bf16x8;
typedef __attribute__((ext_vector_type(4))) float f32x4;
typedef __attribute__((ext_vector_type(4))) int i32x4;

// ---------------- normalize rows of z_i, z_j -> bf16 Z[2N][128] ----------------
__global__ __launch_bounds__(256) void knorm(const float* __restrict__ zi,
                                             const float* __restrict__ zj,
                                             __hip_bfloat16* __restrict__ Z) {
  int w = threadIdx.x >> 6, lane = threadIdx.x & 63;
  int a = blockIdx.x * 4 + w;  // 0..8191, one wave per row
  const float* src = (a < NP) ? (zi + (size_t)a * DD) : (zj + (size_t)(a - NP) * DD);
  float2 v = *(const float2*)(src + lane * 2);
  float ss = v.x * v.x + v.y * v.y;
#pragma unroll
  for (int m = 1; m < 64; m <<= 1) ss += __shfl_xor(ss, m);
  float rn = rsqrtf(ss);
  __hip_bfloat162 o;
  o.x = __float2bfloat16(v.x * rn);
  o.y = __float2bfloat16(v.y * rn);
  *(__hip_bfloat162*)(Z + (size_t)a * DD + lane * 2) = o;
}

// ---------------- label precompute: rowinfo=(y1, 1/rs1, y2, 1/rs2), colinfo=(y1,y2) ----------------
__global__ __launch_bounds__(256) void klabel(const float* __restrict__ labels,
                                              float4* __restrict__ rowinfo,
                                              float2* __restrict__ colinfo) {
  int a = blockIdx.x;  // 0..NP-1
  float ca = labels[a * 2 + 0], ga = labels[a * 2 + 1];
  float s1 = 0.f, cnt = 0.f;
  for (int m = threadIdx.x; m < NP; m += 256) {
    float cm = labels[m * 2 + 0], gm = labels[m * 2 + 1];
    float dy = ca - cm;
    s1 += __expf(-GAMMA1 * dy * dy);
    cnt += (ga == gm) ? 1.f : 0.f;
  }
#pragma unroll
  for (int m = 1; m < 64; m <<= 1) {
    s1 += __shfl_xor(s1, m);
    cnt += __shfl_xor(cnt, m);
  }
  __shared__ float sh[8];
  int w = threadIdx.x >> 6, lane = threadIdx.x & 63;
  if (lane == 0) { sh[w] = s1; sh[4 + w] = cnt; }
  __syncthreads();
  if (threadIdx.x == 0) {
    s1 = sh[0] + sh[1] + sh[2] + sh[3];
    cnt = sh[4] + sh[5] + sh[6] + sh[7];
    float rs1 = 2.f * s1 - 1.f;            // row sum of cont-RBF w, diag removed
    float rs2 = (float)NP + cnt - 1.f;     // row sum of cat w, diag removed
    float4 ri = make_float4(ca, 1.f / rs1, ga, 1.f / rs2);
    rowinfo[a] = ri;
    rowinfo[a + NP] = ri;
    float2 ci = make_float2(ca, ga);
    colinfo[a] = ci;
    colinfo[a + NP] = ci;
  }
}

// ---------------- main: 128x128 tile of S, fused weighted reduction ----------------
// grid (64, 64): blockIdx.y = row tile, blockIdx.x = col tile. 256 threads = 4 waves,
// each wave computes a 64x64 sub-tile via 16x16x32 bf16 MFMA.
__global__ __launch_bounds__(256) void kmain(const __hip_bfloat16* __restrict__ Zp,
                                             const float4* __restrict__ rowinfo,
                                             const float2* __restrict__ colinfo,
                                             float* __restrict__ expsum,
                                             float* __restrict__ wsum) {
  __shared__ char lds[2 * 128 * 256];  // A tile then B tile, 64 KiB, row stride 256 B
  char* ldsA = lds;
  char* ldsB = lds + 128 * 256;
  const int row0 = blockIdx.y * 128, col0 = blockIdx.x * 128;
  const int t = threadIdx.x;
  const char* gZ = (const char*)Zp;  // row-major [8192][256 bytes]

  // stage both tiles, XOR-swizzled: byte_col ^= (row&7)<<4 (kills stride-256B bank conflict)
#pragma unroll
  for (int i = 0; i < 8; ++i) {
    int chunk = t + i * 256;        // 0..2047 chunks of 16B
    int r = chunk >> 4;             // 0..127
    int bc = (chunk & 15) << 4;     // 0..240
    int swz = bc ^ ((r & 7) << 4);
    i32x4 va = *(const i32x4*)(gZ + (size_t)(row0 + r) * 256 + bc);
    *(i32x4*)(ldsA + r * 256 + swz) = va;
    i32x4 vb = *(const i32x4*)(gZ + (size_t)(col0 + r) * 256 + bc);
    *(i32x4*)(ldsB + r * 256 + swz) = vb;
  }
  __syncthreads();

  const int lane = t & 63, w = t >> 6;
  const int wr = w >> 1, wc = w & 1;     // wave's 64x64 quadrant
  const int lrow = lane & 15, lgrp = lane >> 4;

  f32x4 acc[4][4] = {};
#pragma unroll
  for (int kk = 0; kk < 4; ++kk) {       // K = 128 in 4 steps of 32
    int bcol = kk * 64 + (lgrp << 4);    // 16B per lane-group
    bf16x8 af[4], bf[4];
#pragma unroll
    for (int mi = 0; mi < 4; ++mi) {
      int r = wr * 64 + mi * 16 + lrow;
      af[mi] = *(const bf16x8*)(ldsA + r * 256 + (bcol ^ ((r & 7) << 4)));
    }
#pragma unroll
    for (int ni = 0; ni < 4; ++ni) {
      int r = wc * 64 + ni * 16 + lrow;
      bf[ni] = *(const bf16x8*)(ldsB + r * 256 + (bcol ^ ((r & 7) << 4)));
    }
#pragma unroll
    for (int mi = 0; mi < 4; ++mi)
#pragma unroll
      for (int ni = 0; ni < 4; ++ni)
        acc[mi][ni] = __builtin_amdgcn_mfma_f32_16x16x32_bf16(af[mi], bf[ni], acc[mi][ni], 0, 0, 0);
  }

  // epilogue: e = exp(sim-10), wterm = (W1+W2)*sim; per-row reduce, atomic accumulate
  float y1b[4], y2b[4];
  int bcols[4];
#pragma unroll
  for (int ni = 0; ni < 4; ++ni) {
    int b = col0 + wc * 64 + ni * 16 + lrow;
    float2 ci = colinfo[b];
    y1b[ni] = ci.x;
    y2b[ni] = ci.y;
    bcols[ni] = b;
  }
#pragma unroll
  for (int mi = 0; mi < 4; ++mi) {
#pragma unroll
    for (int j = 0; j < 4; ++j) {
      int a = row0 + wr * 64 + mi * 16 + lgrp * 4 + j;  // C/D: row=(lane>>4)*4+reg, col=lane&15
      float4 ri = rowinfo[a];
      float es = 0.f, ws = 0.f;
#pragma unroll
      for (int ni = 0; ni < 4; ++ni) {
        float sim = acc[mi][ni][j] * TINV;
        bool diag = (a == bcols[ni]);
        float e = diag ? 0.f : __expf(sim - SHIFT);
        float dy = ri.x - y1b[ni];
        float w1 = __expf(-GAMMA1 * dy * dy) * ri.y;
        float w2 = ((ri.z == y2b[ni]) ? 1.f : 0.5f) * ri.w;
        float wt = diag ? 0.f : (w1 + w2) * sim;
        es += e;
        ws += wt;
      }
#pragma unroll
      for (int m = 1; m < 16; m <<= 1) {  // reduce across the 16 cols held by this group
        es += __shfl_xor(es, m);
        ws += __shfl_xor(ws, m);
      }
      if (lrow == 0) {
        atomicAdd(&expsum[a], es);
        atomicAdd(&wsum[a], ws);
      }
    }
  }
}

// ---------------- final: loss = -(1/N) * sum_a [ wsum[a] - 2*(SHIFT + log(expsum[a])) ] ----------------
__global__ __launch_bounds__(1024) void kfinal(const float* __restrict__ expsum,
                                               const float* __restrict__ wsum,
                                               float* __restrict__ out) {
  int tid = threadIdx.x;
  float t = 0.f;
  for (int a = tid; a < N2; a += 1024)
    t += wsum[a] - 2.f * (SHIFT + __logf(expsum[a]));
  __shared__ double sh[1024];
  sh[tid] = (double)t;
  __syncthreads();
  for (int s = 512; s > 0; s >>= 1) {
    if (tid < s) sh[tid] += sh[tid + s];
    __syncthreads();
  }
  if (tid == 0) out[0] = (float)(-sh[0] / (double)NP);
}

extern "C" void kernel_launch(void* const* d_in, const int* in_sizes, int n_in,
                              void* d_out, int out_size, void* d_ws, size_t ws_size,
                              hipStream_t stream) {
  const float* zi = (const float*)d_in[0];
  const float* zj = (const float*)d_in[1];
  const float* labels = (const float*)d_in[2];
  float* out = (float*)d_out;
  char* ws = (char*)d_ws;

  float* expsum = (float*)ws;                         // 8192 f32 (32 KiB)
  float* wsum = (float*)(ws + 32 * 1024);             // 8192 f32 (32 KiB)
  float4* rowinfo = (float4*)(ws + 64 * 1024);        // 8192 float4 (128 KiB)
  float2* colinfo = (float2*)(ws + 192 * 1024);       // 8192 float2 (64 KiB)
  __hip_bfloat16* Z = (__hip_bfloat16*)(ws + 256 * 1024);  // 8192x128 bf16 (2 MiB)

  hipMemsetAsync(ws, 0, 64 * 1024, stream);  // zero expsum/wsum every call (replay-safe)
  knorm<<<2048, 256, 0, stream>>>(zi, zj, Z);
  klabel<<<4096, 256, 0, stream>>>(labels, rowinfo, colinfo);
  kmain<<<dim3(64, 64), 256, 0, stream>>>(Z, rowinfo, colinfo, expsum, wsum);
  kfinal<<<1, 1024, 0, stream>>>(expsum, wsum, out);
}

// Round 2
// 153.304 us; speedup vs baseline: 1.2314x; 1.2314x over previous
//
#include <hip/hip_runtime.h>
#include <hip/hip_bf16.h>
#include <math.h>

#define NP 4096      // N
#define DD 128       // D
#define N2 8192      // 2N
#define TINV 10.0f   // 1/temperature
#define SHIFT 10.0f  // fixed lse shift (sim <= 10)
#define C1 14.4269504f       // TINV * log2(e): e = 2^(C1*(acc-1))
#define NGL2 -0.0288539004f  // -GAMMA1 * log2(e), GAMMA1 = 0.02

typedef __attribute__((ext_vector_type(8))) short bf16x8;
typedef __attribute__((ext_vector_type(4))) float f32x4;
typedef __attribute__((ext_vector_type(4))) int i32x4;

// sum over each 16-lane DPP row; result lands in lane (lrow==0) of each row
__device__ __forceinline__ float dpp_red16(float x) {
  x += __int_as_float(__builtin_amdgcn_update_dpp(0, __float_as_int(x), 0x101, 0xF, 0xF, true));
  x += __int_as_float(__builtin_amdgcn_update_dpp(0, __float_as_int(x), 0x102, 0xF, 0xF, true));
  x += __int_as_float(__builtin_amdgcn_update_dpp(0, __float_as_int(x), 0x104, 0xF, 0xF, true));
  x += __int_as_float(__builtin_amdgcn_update_dpp(0, __float_as_int(x), 0x108, 0xF, 0xF, true));
  return x;
}

// ---------------- normalize rows of z_i, z_j -> bf16 Z[2N][128] ----------------
__global__ __launch_bounds__(256) void knorm(const float* __restrict__ zi,
                                             const float* __restrict__ zj,
                                             __hip_bfloat16* __restrict__ Z) {
  int w = threadIdx.x >> 6, lane = threadIdx.x & 63;
  int a = blockIdx.x * 4 + w;
  const float* src = (a < NP) ? (zi + (size_t)a * DD) : (zj + (size_t)(a - NP) * DD);
  float2 v = *(const float2*)(src + lane * 2);
  float ss = v.x * v.x + v.y * v.y;
#pragma unroll
  for (int m = 1; m < 64; m <<= 1) ss += __shfl_xor(ss, m);
  float rn = rsqrtf(ss);
  __hip_bfloat162 o;
  o.x = __float2bfloat16(v.x * rn);
  o.y = __float2bfloat16(v.y * rn);
  *(__hip_bfloat162*)(Z + (size_t)a * DD + lane * 2) = o;
}

// ---------------- label precompute: rowinfo=(y1, TINV/rs1, y2, 1/rs2) ----------------
__global__ __launch_bounds__(256) void klabel(const float* __restrict__ labels,
                                              float4* __restrict__ rowinfo) {
  int a = blockIdx.x;  // 0..NP-1
  float ca = labels[a * 2 + 0], ga = labels[a * 2 + 1];
  float s1 = 0.f, cnt = 0.f;
  for (int m = threadIdx.x; m < NP; m += 256) {
    float cm = labels[m * 2 + 0], gm = labels[m * 2 + 1];
    float dy = ca - cm;
    s1 += __builtin_amdgcn_exp2f(dy * dy * NGL2);
    cnt += (ga == gm) ? 1.f : 0.f;
  }
#pragma unroll
  for (int m = 1; m < 64; m <<= 1) {
    s1 += __shfl_xor(s1, m);
    cnt += __shfl_xor(cnt, m);
  }
  __shared__ float sh[8];
  int w = threadIdx.x >> 6, lane = threadIdx.x & 63;
  if (lane == 0) { sh[w] = s1; sh[4 + w] = cnt; }
  __syncthreads();
  if (threadIdx.x == 0) {
    s1 = sh[0] + sh[1] + sh[2] + sh[3];
    cnt = sh[4] + sh[5] + sh[6] + sh[7];
    float rs1 = 2.f * s1 - 1.f;         // row sum over 8192, diag removed
    float rs2 = (float)NP + cnt - 1.f;  // = 4095 + class count
    float4 ri = make_float4(ca, TINV / rs1, ga, 1.f / rs2);
    rowinfo[a] = ri;
    rowinfo[a + NP] = ri;
  }
}

// ---------------- column sums of Z per cat-class + total: zsc[4][128] ----------------
__global__ __launch_bounds__(256) void kzsum(const __hip_bfloat16* __restrict__ Z,
                                             const float* __restrict__ labels,
                                             float* __restrict__ zsc) {
  int c2 = blockIdx.x;  // column pair 0..63
  float a00 = 0.f, a01 = 0.f, a10 = 0.f, a11 = 0.f, a20 = 0.f, a21 = 0.f;
  for (int r = threadIdx.x; r < N2; r += 256) {
    __hip_bfloat162 v = *(const __hip_bfloat162*)(Z + (size_t)r * DD + c2 * 2);
    float vx = __bfloat162float(v.x), vy = __bfloat162float(v.y);
    float g = labels[(r & (NP - 1)) * 2 + 1];
    float f0 = (g == 0.f) ? 1.f : 0.f, f1 = (g == 1.f) ? 1.f : 0.f, f2 = (g == 2.f) ? 1.f : 0.f;
    a00 = fmaf(f0, vx, a00); a01 = fmaf(f0, vy, a01);
    a10 = fmaf(f1, vx, a10); a11 = fmaf(f1, vy, a11);
    a20 = fmaf(f2, vx, a20); a21 = fmaf(f2, vy, a21);
  }
  float v6[6] = {a00, a01, a10, a11, a20, a21};
#pragma unroll
  for (int k = 0; k < 6; ++k)
#pragma unroll
    for (int m = 1; m < 64; m <<= 1) v6[k] += __shfl_xor(v6[k], m);
  __shared__ float sh[4][6];
  int w = threadIdx.x >> 6, lane = threadIdx.x & 63;
  if (lane == 0)
#pragma unroll
    for (int k = 0; k < 6; ++k) sh[w][k] = v6[k];
  __syncthreads();
  if (threadIdx.x < 2) {
    int comp = threadIdx.x;  // 0 -> x, 1 -> y
    float s0 = sh[0][0 + comp] + sh[1][0 + comp] + sh[2][0 + comp] + sh[3][0 + comp];
    float s1 = sh[0][2 + comp] + sh[1][2 + comp] + sh[2][2 + comp] + sh[3][2 + comp];
    float s2 = sh[0][4 + comp] + sh[1][4 + comp] + sh[2][4 + comp] + sh[3][4 + comp];
    int col = c2 * 2 + comp;
    zsc[0 * DD + col] = s0;
    zsc[1 * DD + col] = s1;
    zsc[2 * DD + col] = s2;
    zsc[3 * DD + col] = s0 + s1 + s2;
  }
}

// ---------------- categorical closed-form: wsum[a] += (0.5(d_tot-1)+0.5(d_cls-1))*TINV/rs2 ----------------
__global__ __launch_bounds__(256) void kcat(const __hip_bfloat16* __restrict__ Z,
                                            const float4* __restrict__ rowinfo,
                                            const float* __restrict__ zsc,
                                            float* __restrict__ wsum) {
  int w = threadIdx.x >> 6, lane = threadIdx.x & 63;
  int a = blockIdx.x * 4 + w;
  float4 ri = rowinfo[a];
  int cls = (int)ri.z;
  __hip_bfloat162 v = *(const __hip_bfloat162*)(Z + (size_t)a * DD + lane * 2);
  float zx = __bfloat162float(v.x), zy = __bfloat162float(v.y);
  const float* zt = zsc + 3 * DD;
  const float* zc = zsc + cls * DD;
  float d1 = zx * zt[lane * 2] + zy * zt[lane * 2 + 1];
  float d2 = zx * zc[lane * 2] + zy * zc[lane * 2 + 1];
#pragma unroll
  for (int m = 1; m < 64; m <<= 1) {
    d1 += __shfl_xor(d1, m);
    d2 += __shfl_xor(d2, m);
  }
  if (lane == 0) {
    float wc = (0.5f * (d1 - 1.0f) + 0.5f * (d2 - 1.0f)) * TINV * ri.w;
    atomicAdd(&wsum[a], wc);
  }
}

// ---------------- main: upper-triangular 128x128 tiles, symmetric fused reduction ----------------
__global__ __launch_bounds__(256, 3) void kmain(const __hip_bfloat16* __restrict__ Zp,
                                                const float4* __restrict__ rowinfo,
                                                float* __restrict__ expsum,
                                                float* __restrict__ wsum) {
  __shared__ char lds[2 * 128 * 128];  // A half-K panel + B half-K panel, 32 KiB
  char* ldsA = lds;
  char* ldsB = lds + 128 * 128;

  // triangular decode: largest I with I*(129-I)/2 <= t
  int tb = blockIdx.x;
  int I = (int)((129.0f - sqrtf(16641.0f - 8.0f * (float)tb)) * 0.5f);
  while (I * (129 - I) / 2 > tb) --I;
  while ((I + 1) * (128 - I) / 2 <= tb) ++I;
  int J = I + (tb - I * (129 - I) / 2);
  const bool diag = (I == J);
  const int row0 = I * 128, col0 = J * 128;
  const int t = threadIdx.x;
  const char* gZ = (const char*)Zp;  // [8192][256B]
  const char* ldsBp = diag ? ldsA : ldsB;

  const int lane = t & 63, w = t >> 6;
  const int wr = w >> 1, wc = w & 1;
  const int lrow = lane & 15, lgrp = lane >> 4;

  f32x4 acc[4][4] = {};
#pragma unroll
  for (int kh = 0; kh < 2; ++kh) {  // two K-halves of 64
    if (kh) __syncthreads();        // protect lds from previous compute
#pragma unroll
    for (int i = 0; i < 4; ++i) {   // stage A half: 1024 x 16B chunks
      int chunk = t + i * 256;
      int r = chunk >> 3;
      int bc = (chunk & 7) << 4;
      int swz = bc ^ ((r & 7) << 4);
      i32x4 va = *(const i32x4*)(gZ + (size_t)(row0 + r) * 256 + kh * 128 + bc);
      *(i32x4*)(ldsA + r * 128 + swz) = va;
    }
    if (!diag) {
#pragma unroll
      for (int i = 0; i < 4; ++i) {
        int chunk = t + i * 256;
        int r = chunk >> 3;
        int bc = (chunk & 7) << 4;
        int swz = bc ^ ((r & 7) << 4);
        i32x4 vb = *(const i32x4*)(gZ + (size_t)(col0 + r) * 256 + kh * 128 + bc);
        *(i32x4*)(ldsB + r * 128 + swz) = vb;
      }
    }
    __syncthreads();
#pragma unroll
    for (int kk = 0; kk < 2; ++kk) {
      int bcol = kk * 64 + (lgrp << 4);
      bf16x8 af[4], bfv[4];
#pragma unroll
      for (int mi = 0; mi < 4; ++mi) {
        int r = wr * 64 + mi * 16 + lrow;
        af[mi] = *(const bf16x8*)(ldsA + r * 128 + (bcol ^ ((r & 7) << 4)));
      }
#pragma unroll
      for (int ni = 0; ni < 4; ++ni) {
        int r = wc * 64 + ni * 16 + lrow;
        bfv[ni] = *(const bf16x8*)(ldsBp + r * 128 + (bcol ^ ((r & 7) << 4)));
      }
#pragma unroll
      for (int mi = 0; mi < 4; ++mi)
#pragma unroll
        for (int ni = 0; ni < 4; ++ni)
          acc[mi][ni] = __builtin_amdgcn_mfma_f32_16x16x32_bf16(af[mi], bfv[ni], acc[mi][ni], 0, 0, 0);
    }
    if (kh == 0) __syncthreads();
  }

  // epilogue. acc element j of (mi,ni): row a = row0+wr*64+mi*16+lgrp*4+j, col b = col0+wc*64+ni*16+lrow
  float4 rbv[4];
  int bcols[4];
#pragma unroll
  for (int ni = 0; ni < 4; ++ni) {
    int b = col0 + wc * 64 + ni * 16 + lrow;
    rbv[ni] = rowinfo[b];
    bcols[ni] = b;
  }

  if (!diag) {
    float ec[4] = {0.f, 0.f, 0.f, 0.f}, pc[4] = {0.f, 0.f, 0.f, 0.f};
#pragma unroll
    for (int mi = 0; mi < 4; ++mi) {
      int a0 = row0 + wr * 64 + mi * 16 + lgrp * 4;
#pragma unroll
      for (int j = 0; j < 4; ++j) {
        int a = a0 + j;
        float4 ri = rowinfo[a];
        float es = 0.f, pa = 0.f;
#pragma unroll
        for (int ni = 0; ni < 4; ++ni) {
          float v = acc[mi][ni][j];
          float e = __builtin_amdgcn_exp2f(fmaf(v, C1, -C1));  // exp(sim-10)
          float dy = ri.x - rbv[ni].x;
          float wu = __builtin_amdgcn_exp2f(dy * dy * NGL2);   // exp(-g*dy^2)
          es += e;
          ec[ni] += e;
          pa = fmaf(wu, v, pa);
          pc[ni] = fmaf(wu, v, pc[ni]);
        }
        es = dpp_red16(es);
        pa = dpp_red16(pa);
        if (lrow == 0) {
          atomicAdd(&expsum[a], es);
          atomicAdd(&wsum[a], pa * ri.y);  // ri.y = TINV/rs1
        }
      }
    }
    // column-side (transpose) contributions
#pragma unroll
    for (int ni = 0; ni < 4; ++ni) {
      float e2 = ec[ni] + __shfl_xor(ec[ni], 16);
      e2 += __shfl_xor(e2, 32);
      float p2 = pc[ni] + __shfl_xor(pc[ni], 16);
      p2 += __shfl_xor(p2, 32);
      if (lane < 16) {
        atomicAdd(&expsum[bcols[ni]], e2);
        atomicAdd(&wsum[bcols[ni]], p2 * rbv[ni].y);
      }
    }
  } else {
#pragma unroll
    for (int mi = 0; mi < 4; ++mi) {
      int a0 = row0 + wr * 64 + mi * 16 + lgrp * 4;
#pragma unroll
      for (int j = 0; j < 4; ++j) {
        int a = a0 + j;
        float4 ri = rowinfo[a];
        float es = 0.f, pa = 0.f;
#pragma unroll
        for (int ni = 0; ni < 4; ++ni) {
          float v = acc[mi][ni][j];
          float nd = (a != bcols[ni]) ? 1.f : 0.f;
          float e = __builtin_amdgcn_exp2f(fmaf(v, C1, -C1)) * nd;
          float dy = ri.x - rbv[ni].x;
          float wu = __builtin_amdgcn_exp2f(dy * dy * NGL2) * nd;
          es += e;
          pa = fmaf(wu, v, pa);
        }
        es = dpp_red16(es);
        pa = dpp_red16(pa);
        if (lrow == 0) {
          atomicAdd(&expsum[a], es);
          atomicAdd(&wsum[a], pa * ri.y);
        }
      }
    }
  }
}

// ---------------- final: loss = -(1/N) * sum_a [ wsum[a] - 2*(SHIFT + log(expsum[a])) ] ----------------
__global__ __launch_bounds__(1024) void kfinal(const float* __restrict__ expsum,
                                               const float* __restrict__ wsum,
                                               float* __restrict__ out) {
  int tid = threadIdx.x;
  float t = 0.f;
  for (int a = tid; a < N2; a += 1024)
    t += wsum[a] - 2.f * (SHIFT + __logf(expsum[a]));
  __shared__ double sh[1024];
  sh[tid] = (double)t;
  __syncthreads();
  for (int s = 512; s > 0; s >>= 1) {
    if (tid < s) sh[tid] += sh[tid + s];
    __syncthreads();
  }
  if (tid == 0) out[0] = (float)(-sh[0] / (double)NP);
}

extern "C" void kernel_launch(void* const* d_in, const int* in_sizes, int n_in,
                              void* d_out, int out_size, void* d_ws, size_t ws_size,
                              hipStream_t stream) {
  const float* zi = (const float*)d_in[0];
  const float* zj = (const float*)d_in[1];
  const float* labels = (const float*)d_in[2];
  float* out = (float*)d_out;
  char* ws = (char*)d_ws;

  float* expsum = (float*)ws;                              // 32 KiB
  float* wsum = (float*)(ws + 32 * 1024);                  // 32 KiB
  float4* rowinfo = (float4*)(ws + 64 * 1024);             // 128 KiB
  float* zsc = (float*)(ws + 192 * 1024);                  // 4x128 f32 (2 KiB)
  __hip_bfloat16* Z = (__hip_bfloat16*)(ws + 256 * 1024);  // 2 MiB

  hipMemsetAsync(ws, 0, 64 * 1024, stream);  // zero expsum/wsum (replay-safe)
  knorm<<<2048, 256, 0, stream>>>(zi, zj, Z);
  klabel<<<4096, 256, 0, stream>>>(labels, rowinfo);
  kzsum<<<64, 256, 0, stream>>>(Z, labels, zsc);
  kcat<<<2048, 256, 0, stream>>>(Z, rowinfo, zsc, wsum);
  kmain<<<2080, 256, 0, stream>>>(Z, rowinfo, expsum, wsum);
  kfinal<<<1, 1024, 0, stream>>>(expsum, wsum, out);
}

// Round 3
// 79.989 us; speedup vs baseline: 2.3601x; 1.9166x over previous
//
#include <hip/hip_runtime.h>
#include <hip/hip_bf16.h>
#include <math.h>

#define NP 4096      // N
#define DD 128       // D
#define N2 8192      // 2N
#define TINV 10.0f   // 1/temperature
#define SHIFT 10.0f  // fixed lse shift (sim <= 10)
#define C1 14.4269504f       // TINV * log2(e): e = 2^(C1*(acc-1))
#define NGL2 -0.0288539004f  // -GAMMA1 * log2(e), GAMMA1 = 0.02

typedef __attribute__((ext_vector_type(8))) short bf16x8;
typedef __attribute__((ext_vector_type(4))) float f32x4;
typedef __attribute__((ext_vector_type(4))) int i32x4;

// sum over each 16-lane DPP row; result lands in lane (lrow==0) of each row
__device__ __forceinline__ float dpp_red16(float x) {
  x += __int_as_float(__builtin_amdgcn_update_dpp(0, __float_as_int(x), 0x101, 0xF, 0xF, true));
  x += __int_as_float(__builtin_amdgcn_update_dpp(0, __float_as_int(x), 0x102, 0xF, 0xF, true));
  x += __int_as_float(__builtin_amdgcn_update_dpp(0, __float_as_int(x), 0x104, 0xF, 0xF, true));
  x += __int_as_float(__builtin_amdgcn_update_dpp(0, __float_as_int(x), 0x108, 0xF, 0xF, true));
  return x;
}

// ---------------- normalize rows of z_i, z_j -> bf16 Z[2N][128] ----------------
__global__ __launch_bounds__(256) void knorm(const float* __restrict__ zi,
                                             const float* __restrict__ zj,
                                             __hip_bfloat16* __restrict__ Z) {
  int w = threadIdx.x >> 6, lane = threadIdx.x & 63;
  int a = blockIdx.x * 4 + w;
  const float* src = (a < NP) ? (zi + (size_t)a * DD) : (zj + (size_t)(a - NP) * DD);
  float2 v = *(const float2*)(src + lane * 2);
  float ss = v.x * v.x + v.y * v.y;
#pragma unroll
  for (int m = 1; m < 64; m <<= 1) ss += __shfl_xor(ss, m);
  float rn = rsqrtf(ss);
  __hip_bfloat162 o;
  o.x = __float2bfloat16(v.x * rn);
  o.y = __float2bfloat16(v.y * rn);
  *(__hip_bfloat162*)(Z + (size_t)a * DD + lane * 2) = o;
}

// ---------------- label precompute: rowinfo=(y1, TINV/rs1, y2, 1/rs2) ----------------
__global__ __launch_bounds__(256) void klabel(const float* __restrict__ labels,
                                              float4* __restrict__ rowinfo) {
  int a = blockIdx.x;  // 0..NP-1
  float ca = labels[a * 2 + 0], ga = labels[a * 2 + 1];
  float s1 = 0.f, cnt = 0.f;
  for (int m = threadIdx.x; m < NP; m += 256) {
    float cm = labels[m * 2 + 0], gm = labels[m * 2 + 1];
    float dy = ca - cm;
    s1 += __builtin_amdgcn_exp2f(dy * dy * NGL2);
    cnt += (ga == gm) ? 1.f : 0.f;
  }
#pragma unroll
  for (int m = 1; m < 64; m <<= 1) {
    s1 += __shfl_xor(s1, m);
    cnt += __shfl_xor(cnt, m);
  }
  __shared__ float sh[8];
  int w = threadIdx.x >> 6, lane = threadIdx.x & 63;
  if (lane == 0) { sh[w] = s1; sh[4 + w] = cnt; }
  __syncthreads();
  if (threadIdx.x == 0) {
    s1 = sh[0] + sh[1] + sh[2] + sh[3];
    cnt = sh[4] + sh[5] + sh[6] + sh[7];
    float rs1 = 2.f * s1 - 1.f;         // row sum over 8192, diag removed
    float rs2 = (float)NP + cnt - 1.f;  // = 4095 + class count
    float4 ri = make_float4(ca, TINV / rs1, ga, 1.f / rs2);
    rowinfo[a] = ri;
    rowinfo[a + NP] = ri;
  }
}

// ---------------- column sums of Z per cat-class + total: zsc[4][128] ----------------
__global__ __launch_bounds__(256) void kzsum(const __hip_bfloat16* __restrict__ Z,
                                             const float* __restrict__ labels,
                                             float* __restrict__ zsc) {
  int c2 = blockIdx.x;  // column pair 0..63
  float a00 = 0.f, a01 = 0.f, a10 = 0.f, a11 = 0.f, a20 = 0.f, a21 = 0.f;
  for (int r = threadIdx.x; r < N2; r += 256) {
    __hip_bfloat162 v = *(const __hip_bfloat162*)(Z + (size_t)r * DD + c2 * 2);
    float vx = __bfloat162float(v.x), vy = __bfloat162float(v.y);
    float g = labels[(r & (NP - 1)) * 2 + 1];
    float f0 = (g == 0.f) ? 1.f : 0.f, f1 = (g == 1.f) ? 1.f : 0.f, f2 = (g == 2.f) ? 1.f : 0.f;
    a00 = fmaf(f0, vx, a00); a01 = fmaf(f0, vy, a01);
    a10 = fmaf(f1, vx, a10); a11 = fmaf(f1, vy, a11);
    a20 = fmaf(f2, vx, a20); a21 = fmaf(f2, vy, a21);
  }
  float v6[6] = {a00, a01, a10, a11, a20, a21};
#pragma unroll
  for (int k = 0; k < 6; ++k)
#pragma unroll
    for (int m = 1; m < 64; m <<= 1) v6[k] += __shfl_xor(v6[k], m);
  __shared__ float sh[4][6];
  int w = threadIdx.x >> 6, lane = threadIdx.x & 63;
  if (lane == 0)
#pragma unroll
    for (int k = 0; k < 6; ++k) sh[w][k] = v6[k];
  __syncthreads();
  if (threadIdx.x < 2) {
    int comp = threadIdx.x;  // 0 -> x, 1 -> y
    float s0 = sh[0][0 + comp] + sh[1][0 + comp] + sh[2][0 + comp] + sh[3][0 + comp];
    float s1 = sh[0][2 + comp] + sh[1][2 + comp] + sh[2][2 + comp] + sh[3][2 + comp];
    float s2 = sh[0][4 + comp] + sh[1][4 + comp] + sh[2][4 + comp] + sh[3][4 + comp];
    int col = c2 * 2 + comp;
    zsc[0 * DD + col] = s0;
    zsc[1 * DD + col] = s1;
    zsc[2 * DD + col] = s2;
    zsc[3 * DD + col] = s0 + s1 + s2;
  }
}

// ---------------- categorical closed-form: catw[a] = (0.5(d_tot-1)+0.5(d_cls-1))*TINV/rs2 ----------------
__global__ __launch_bounds__(256) void kcat(const __hip_bfloat16* __restrict__ Z,
                                            const float4* __restrict__ rowinfo,
                                            const float* __restrict__ zsc,
                                            float* __restrict__ catw) {
  int w = threadIdx.x >> 6, lane = threadIdx.x & 63;
  int a = blockIdx.x * 4 + w;
  float4 ri = rowinfo[a];
  int cls = (int)ri.z;
  __hip_bfloat162 v = *(const __hip_bfloat162*)(Z + (size_t)a * DD + lane * 2);
  float zx = __bfloat162float(v.x), zy = __bfloat162float(v.y);
  const float* zt = zsc + 3 * DD;
  const float* zc = zsc + cls * DD;
  float d1 = zx * zt[lane * 2] + zy * zt[lane * 2 + 1];
  float d2 = zx * zc[lane * 2] + zy * zc[lane * 2 + 1];
#pragma unroll
  for (int m = 1; m < 64; m <<= 1) {
    d1 += __shfl_xor(d1, m);
    d2 += __shfl_xor(d2, m);
  }
  if (lane == 0) {
    catw[a] = (0.5f * (d1 - 1.0f) + 0.5f * (d2 - 1.0f)) * TINV * ri.w;
  }
}

// ---------------- main: upper-triangular 128x128 tiles, partials to per-block slots ----------------
// part[tb] is float2[256]: [0..127] row-side (es, ws), [128..255] col-side (es, ws).
// Diag blocks leave the col-side half unwritten/garbage; the reducer never reads it.
__global__ __launch_bounds__(256, 3) void kmain(const __hip_bfloat16* __restrict__ Zp,
                                                const float4* __restrict__ rowinfo,
                                                float2* __restrict__ part) {
  __shared__ char lds[2 * 128 * 128];  // A half-K panel + B half-K panel, 32 KiB
  char* ldsA = lds;
  char* ldsB = lds + 128 * 128;

  // triangular decode: largest I with I*(129-I)/2 <= tb
  int tb = blockIdx.x;
  int I = (int)((129.0f - sqrtf(16641.0f - 8.0f * (float)tb)) * 0.5f);
  while (I * (129 - I) / 2 > tb) --I;
  while ((I + 1) * (128 - I) / 2 <= tb) ++I;
  int J = I + (tb - I * (129 - I) / 2);
  const bool diag = (I == J);
  const int row0 = I * 128, col0 = J * 128;
  const int t = threadIdx.x;
  const char* gZ = (const char*)Zp;  // [8192][256B]
  const char* ldsBp = diag ? ldsA : ldsB;

  const int lane = t & 63, w = t >> 6;
  const int wr = w >> 1, wc = w & 1;
  const int lrow = lane & 15, lgrp = lane >> 4;

  f32x4 acc[4][4] = {};
#pragma unroll
  for (int kh = 0; kh < 2; ++kh) {  // two K-halves of 64
    if (kh) __syncthreads();
#pragma unroll
    for (int i = 0; i < 4; ++i) {   // stage A half: 1024 x 16B chunks
      int chunk = t + i * 256;
      int r = chunk >> 3;
      int bc = (chunk & 7) << 4;
      int swz = bc ^ ((r & 7) << 4);
      i32x4 va = *(const i32x4*)(gZ + (size_t)(row0 + r) * 256 + kh * 128 + bc);
      *(i32x4*)(ldsA + r * 128 + swz) = va;
    }
    if (!diag) {
#pragma unroll
      for (int i = 0; i < 4; ++i) {
        int chunk = t + i * 256;
        int r = chunk >> 3;
        int bc = (chunk & 7) << 4;
        int swz = bc ^ ((r & 7) << 4);
        i32x4 vb = *(const i32x4*)(gZ + (size_t)(col0 + r) * 256 + kh * 128 + bc);
        *(i32x4*)(ldsB + r * 128 + swz) = vb;
      }
    }
    __syncthreads();
#pragma unroll
    for (int kk = 0; kk < 2; ++kk) {
      int bcol = kk * 64 + (lgrp << 4);
      bf16x8 af[4], bfv[4];
#pragma unroll
      for (int mi = 0; mi < 4; ++mi) {
        int r = wr * 64 + mi * 16 + lrow;
        af[mi] = *(const bf16x8*)(ldsA + r * 128 + (bcol ^ ((r & 7) << 4)));
      }
#pragma unroll
      for (int ni = 0; ni < 4; ++ni) {
        int r = wc * 64 + ni * 16 + lrow;
        bfv[ni] = *(const bf16x8*)(ldsBp + r * 128 + (bcol ^ ((r & 7) << 4)));
      }
#pragma unroll
      for (int mi = 0; mi < 4; ++mi)
#pragma unroll
        for (int ni = 0; ni < 4; ++ni)
          acc[mi][ni] = __builtin_amdgcn_mfma_f32_16x16x32_bf16(af[mi], bfv[ni], acc[mi][ni], 0, 0, 0);
    }
  }

  // epilogue. acc element j of (mi,ni): row a = row0+wr*64+mi*16+lgrp*4+j, col b = col0+wc*64+ni*16+lrow
  float4 rbv[4];
#pragma unroll
  for (int ni = 0; ni < 4; ++ni) rbv[ni] = rowinfo[col0 + wc * 64 + ni * 16 + lrow];

  float rese[4][4], resw[4][4];  // per-(mi,j) row partials, valid on lrow==0 lanes
  float2 cv[4];                  // per-ni col partials (all lanes; lanes<16 valid)

  if (!diag) {
    float ec[4] = {0.f, 0.f, 0.f, 0.f}, pc[4] = {0.f, 0.f, 0.f, 0.f};
#pragma unroll
    for (int mi = 0; mi < 4; ++mi) {
      int a0 = row0 + wr * 64 + mi * 16 + lgrp * 4;
#pragma unroll
      for (int j = 0; j < 4; ++j) {
        float4 ri = rowinfo[a0 + j];
        float es = 0.f, pa = 0.f;
#pragma unroll
        for (int ni = 0; ni < 4; ++ni) {
          float v = acc[mi][ni][j];
          float e = __builtin_amdgcn_exp2f(fmaf(v, C1, -C1));  // exp(sim-10)
          float dy = ri.x - rbv[ni].x;
          float wu = __builtin_amdgcn_exp2f(dy * dy * NGL2);   // exp(-g*dy^2)
          es += e;
          ec[ni] += e;
          pa = fmaf(wu, v, pa);
          pc[ni] = fmaf(wu, v, pc[ni]);
        }
        rese[mi][j] = dpp_red16(es);
        resw[mi][j] = dpp_red16(pa) * ri.y;  // ri.y = TINV/rs1
      }
    }
#pragma unroll
    for (int ni = 0; ni < 4; ++ni) {
      float e2 = ec[ni] + __shfl_xor(ec[ni], 16);
      e2 += __shfl_xor(e2, 32);
      float p2 = pc[ni] + __shfl_xor(pc[ni], 16);
      p2 += __shfl_xor(p2, 32);
      cv[ni] = make_float2(e2, p2 * rbv[ni].y);
    }
  } else {
    int bcols[4];
#pragma unroll
    for (int ni = 0; ni < 4; ++ni) bcols[ni] = col0 + wc * 64 + ni * 16 + lrow;
#pragma unroll
    for (int mi = 0; mi < 4; ++mi) {
      int a0 = row0 + wr * 64 + mi * 16 + lgrp * 4;
#pragma unroll
      for (int j = 0; j < 4; ++j) {
        int a = a0 + j;
        float4 ri = rowinfo[a];
        float es = 0.f, pa = 0.f;
#pragma unroll
        for (int ni = 0; ni < 4; ++ni) {
          float v = acc[mi][ni][j];
          float nd = (a != bcols[ni]) ? 1.f : 0.f;
          float e = __builtin_amdgcn_exp2f(fmaf(v, C1, -C1)) * nd;
          float dy = ri.x - rbv[ni].x;
          float wu = __builtin_amdgcn_exp2f(dy * dy * NGL2) * nd;
          es += e;
          pa = fmaf(wu, v, pa);
        }
        rese[mi][j] = dpp_red16(es);
        resw[mi][j] = dpp_red16(pa) * ri.y;
      }
    }
  }

  // combine across waves in LDS (reuse staging buffer), then one coalesced write
  float2* lds2 = (float2*)lds;  // [0..127] rows, [128..255] cols
  __syncthreads();              // all ds_reads of staging data complete
  if (wc == 0 && lrow == 0) {
#pragma unroll
    for (int mi = 0; mi < 4; ++mi)
#pragma unroll
      for (int j = 0; j < 4; ++j)
        lds2[wr * 64 + mi * 16 + lgrp * 4 + j] = make_float2(rese[mi][j], resw[mi][j]);
  }
  if (!diag && wr == 0 && lane < 16) {
#pragma unroll
    for (int ni = 0; ni < 4; ++ni) lds2[128 + wc * 64 + ni * 16 + lane] = cv[ni];
  }
  __syncthreads();
  if (wc == 1 && lrow == 0) {
#pragma unroll
    for (int mi = 0; mi < 4; ++mi)
#pragma unroll
      for (int j = 0; j < 4; ++j) {
        int idx = wr * 64 + mi * 16 + lgrp * 4 + j;
        float2 o = lds2[idx];
        o.x += rese[mi][j];
        o.y += resw[mi][j];
        lds2[idx] = o;
      }
  }
  if (!diag && wr == 1 && lane < 16) {
#pragma unroll
    for (int ni = 0; ni < 4; ++ni) {
      int idx = 128 + wc * 64 + ni * 16 + lane;
      float2 o = lds2[idx];
      o.x += cv[ni].x;
      o.y += cv[ni].y;
      lds2[idx] = o;
    }
  }
  __syncthreads();
  part[(size_t)tb * 256 + t] = lds2[t];
}

// ---------------- reduce per-tile: fold 64 slots, add catw, apply log ----------------
__global__ __launch_bounds__(128) void kreduce(const float2* __restrict__ part,
                                               const float* __restrict__ catw,
                                               double* __restrict__ tilesum) {
  int T = blockIdx.x;   // 0..63
  int r = threadIdx.x;  // 0..127
  float es = 0.f, ws = 0.f;
  int tb0 = T * (129 - T) / 2;
  for (int k = 0; k < 64 - T; ++k) {  // row-side: blocks (T, J>=T), contiguous tb
    float2 v = part[(size_t)(tb0 + k) * 256 + r];
    es += v.x;
    ws += v.y;
  }
  for (int I = 0; I < T; ++I) {       // col-side: blocks (I<T, T)
    float2 v = part[(size_t)(I * (129 - I) / 2 + T - I) * 256 + 128 + r];
    es += v.x;
    ws += v.y;
  }
  ws += catw[T * 128 + r];
  double val = (double)ws - 2.0 * (double)(SHIFT + __logf(es));
#pragma unroll
  for (int m = 1; m < 64; m <<= 1) val += __shfl_xor(val, m);
  __shared__ double sh[2];
  if ((threadIdx.x & 63) == 0) sh[threadIdx.x >> 6] = val;
  __syncthreads();
  if (threadIdx.x == 0) tilesum[T] = sh[0] + sh[1];
}

// ---------------- final: loss = -(1/N) * sum of tile sums ----------------
__global__ __launch_bounds__(64) void kfinal(const double* __restrict__ tilesum,
                                             float* __restrict__ out) {
  double v = tilesum[threadIdx.x];
#pragma unroll
  for (int m = 1; m < 64; m <<= 1) v += __shfl_xor(v, m);
  if (threadIdx.x == 0) out[0] = (float)(-v / (double)NP);
}

extern "C" void kernel_launch(void* const* d_in, const int* in_sizes, int n_in,
                              void* d_out, int out_size, void* d_ws, size_t ws_size,
                              hipStream_t stream) {
  const float* zi = (const float*)d_in[0];
  const float* zj = (const float*)d_in[1];
  const float* labels = (const float*)d_in[2];
  float* out = (float*)d_out;
  char* ws = (char*)d_ws;

  float4* rowinfo = (float4*)ws;                            // 128 KiB
  float* zsc = (float*)(ws + 128 * 1024);                   // 2 KiB
  float* catw = (float*)(ws + 136 * 1024);                  // 32 KiB
  double* tilesum = (double*)(ws + 170 * 1024);             // 512 B
  __hip_bfloat16* Z = (__hip_bfloat16*)(ws + 256 * 1024);   // 2 MiB
  float2* part = (float2*)(ws + 256 * 1024 + 2 * 1024 * 1024);  // 2080*256*8B = 4.16 MiB

  knorm<<<2048, 256, 0, stream>>>(zi, zj, Z);
  klabel<<<4096, 256, 0, stream>>>(labels, rowinfo);
  kzsum<<<64, 256, 0, stream>>>(Z, labels, zsc);
  kcat<<<2048, 256, 0, stream>>>(Z, rowinfo, zsc, catw);
  kmain<<<2080, 256, 0, stream>>>(Z, rowinfo, part);
  kreduce<<<64, 128, 0, stream>>>(part, catw, tilesum);
  kfinal<<<1, 64, 0, stream>>>(tilesum, out);
}